// Round 10
// baseline (392.079 us; speedup 1.0000x reference)
//
#include <hip/hip_runtime.h>
#include <math.h>

#define T_STEPS 12
#define HID 64
#define HSTR2 68            // h-tile row stride in u32 (64 + 4 pad -> 2-way banks = free)
#define HTSZ (16*HSTR2)     // 1088 u32 per h buffer

typedef __attribute__((ext_vector_type(8))) short short8;
typedef __attribute__((ext_vector_type(4))) float floatx4;

__device__ __forceinline__ unsigned prm(unsigned a, unsigned b, unsigned s){
  return __builtin_amdgcn_perm(a, b, s);
}
__device__ __forceinline__ float sigmoid2_(float x){
  return 1.0f/(1.0f + __expf(-x));
}
__device__ __forceinline__ float tanh2_(float x){
  return 1.0f - 2.0f/(1.0f + __expf(2.0f*x));
}
__device__ __forceinline__ unsigned short f2bf(float x){   // RNE (packB only)
  unsigned u = __float_as_uint(x);
  return (unsigned short)((u + 0x7FFFu + ((u >> 16) & 1u)) >> 16);
}
__device__ __forceinline__ float bf2f(unsigned short h){
  return __uint_as_float(((unsigned)h) << 16);
}

// --- CSR build ----------------------------------------------------------
__global__ void count_kernel(const int* __restrict__ ei, int E, int* __restrict__ cnt){
  int e = blockIdx.x*blockDim.x + threadIdx.x;
  if (e < E) atomicAdd(&cnt[ei[E + e]], 1);
}

__global__ void dinv_scale_kernel(const int* __restrict__ cnt, const float* __restrict__ x,
                                  float* __restrict__ dinv, float4* __restrict__ xs, int N){
  int tid = blockIdx.x*blockDim.x + threadIdx.x;
  if (tid >= N*6) return;
  int n = tid / 6;
  float dn = rsqrtf((float)cnt[n] + 1.0f);
  if ((tid - n*6) == 0) dinv[n] = dn;
  float4 v = ((const float4*)x)[tid];
  xs[tid] = make_float4(dn*v.x, dn*v.y, dn*v.z, dn*v.w);
}

__global__ void scan1_kernel(const int* __restrict__ cnt, int* __restrict__ part,
                             int* __restrict__ bsum, int N){
  __shared__ int sm[1024];
  int tid = threadIdx.x;
  int g = blockIdx.x*1024 + tid;
  int v = (g < N) ? cnt[g] : 0;
  sm[tid] = v; __syncthreads();
  for (int off = 1; off < 1024; off <<= 1){
    int t = (tid >= off) ? sm[tid-off] : 0;
    __syncthreads();
    sm[tid] += t;
    __syncthreads();
  }
  if (g < N) part[g] = sm[tid];
  if (tid == 1023) bsum[blockIdx.x] = sm[1023];
}
__global__ void scan2_kernel(const int* __restrict__ bsum, int* __restrict__ bincl, int nb){
  int lane = threadIdx.x;
  int v = (lane < nb) ? bsum[lane] : 0;
  #pragma unroll
  for (int off = 1; off < 64; off <<= 1){
    int u = __shfl_up(v, off, 64);
    if (lane >= off) v += u;
  }
  if (lane < nb) bincl[lane] = v;
}
__global__ void scan3_kernel(const int* __restrict__ part, const int* __restrict__ bincl,
                             const int* __restrict__ cnt, int* __restrict__ row_start,
                             int* __restrict__ cursor, int N){
  int g = blockIdx.x*blockDim.x + threadIdx.x;
  if (g < N){
    int b = g >> 10;
    int incl = part[g] + (b ? bincl[b-1] : 0);
    int excl = incl - cnt[g];
    row_start[g] = excl;
    cursor[g]    = excl;
    if (g == N-1) row_start[N] = incl;
  }
}
__global__ void fill_kernel(const int* __restrict__ ei, int E,
                            int* __restrict__ cursor, int* __restrict__ csr){
  int e = blockIdx.x*blockDim.x + threadIdx.x;
  if (e < E){
    int dst = ei[E + e];
    int pos = atomicAdd(&cursor[dst], 1);
    csr[pos] = ei[e];  // src
  }
}

__global__ void gather6_kernel(const float4* __restrict__ xs, const int* __restrict__ row_start,
                               const int* __restrict__ csr, const float* __restrict__ dinv,
                               float4* __restrict__ rin, int N){
  int tid = blockIdx.x*blockDim.x + threadIdx.x;
  if (tid >= N*6) return;
  int n = tid / 6;
  int q = tid - n*6;
  int s0 = row_start[n], s1 = row_start[n+1];
  float4 acc = xs[n*6 + q];          // self term
  int e = s0;
  for (; e + 1 < s1; e += 2){
    int sa = csr[e], sb = csr[e+1];
    float4 va = xs[sa*6 + q];
    float4 vb = xs[sb*6 + q];
    acc.x += va.x + vb.x;
    acc.y += va.y + vb.y;
    acc.z += va.z + vb.z;
    acc.w += va.w + vb.w;
  }
  if (e < s1){
    float4 va = xs[csr[e]*6 + q];
    acc.x += va.x; acc.y += va.y; acc.z += va.z; acc.w += va.w;
  }
  float dn = dinv[n];
  rin[tid] = make_float4(dn*acc.x, dn*acc.y, dn*acc.z, dn*acc.w);
}

// Pack weights into split-bf16 B-fragment layout (round-6 proven layout).
__global__ void packB_kernel(const float* __restrict__ W_ih, const float* __restrict__ W_hh,
                             unsigned short* __restrict__ Bpk){
  int idx = blockIdx.x*blockDim.x + threadIdx.x;
  if (idx >= 48*512) return;
  int q = idx >> 9;
  int rr = idx & 511;
  int l = rr >> 3, j = rr & 7;
  int g, c4, kt;
  if (q < 32){ g = q >> 4; int rem = q & 15; c4 = rem >> 2; kt = rem & 3; }
  else if (q < 40){ g = 2; c4 = (q-32) >> 1; kt = (q-32) & 1; }
  else            { g = 3; c4 = (q-40) >> 1; kt = ((q-40) & 1) + 2; }
  int k  = kt*32 + (l >> 4)*8 + j;
  int n  = l & 15;
  int jc = c4*16 + n;
  float w;
  if (g == 0)      w = (k < 64) ? W_ih[jc*64 + k]      : W_hh[jc*64 + (k-64)];
  else if (g == 1) w = (k < 64) ? W_ih[(64+jc)*64 + k] : W_hh[(64+jc)*64 + (k-64)];
  else if (g == 2) w = W_ih[(128+jc)*64 + k];
  else             w = W_hh[(128+jc)*64 + (k-64)];
  unsigned short hi = f2bf(w);
  unsigned short lo = f2bf(w - bf2f(hi));
  Bpk[q*512 + l*8 + j]         = hi;
  Bpk[24576 + q*512 + l*8 + j] = lo;
}

// Fused 12-step GRU + FC. NEW STRUCTURE: 4 waves cooperate on one 16-node
// tile; wave c4 owns 16 output channels and holds ITS B-fragments (24 short8
// = 96 VGPRs) in registers across all timesteps -> zero per-t B LDS traffic.
// h exchanged via a tiny double-buffered 16x64 LDS tile, one barrier per t.
// LDS ~18 KB; occupancy VGPR-bound at 2 waves/EU (waves_per_eu(2,2) -> 256).
__global__ __attribute__((amdgpu_waves_per_eu(2, 2))) __launch_bounds__(512)
void gru4_kernel(const float* __restrict__ rin,
                 const float* __restrict__ W_gcn, const float* __restrict__ b_gcn,
                 const unsigned short* __restrict__ Bpk,
                 const float* __restrict__ b_ih, const float* __restrict__ b_hh,
                 const float* __restrict__ W_fc, const float* __restrict__ b_fc,
                 float* __restrict__ out, int N, int ntiles){
  __shared__ unsigned hbuf[2][2][HTSZ];   // [group][buf][row*HSTR2+col]
  __shared__ float wgl[192];              // wg0 | wg1 | bg

  if (threadIdx.x < 64){
    wgl[threadIdx.x]       = W_gcn[threadIdx.x];
    wgl[64 + threadIdx.x]  = W_gcn[64 + threadIdx.x];
    wgl[128 + threadIdx.x] = b_gcn[threadIdx.x];
  }

  int lane  = threadIdx.x & 63;
  int wid   = threadIdx.x >> 6;
  int group = wid >> 2;        // 2 tile-groups per block
  int c4    = wid & 3;         // this wave's output-channel group
  int tile  = blockIdx.x*2 + group;
  if (tile > ntiles-1) tile = ntiles-1;   // clamp: duplicate work, benign
  int n0   = tile << 4;
  int quad = lane >> 4;
  int n16  = lane & 15;

  // zero both h buffers for this group (4 waves x 64 lanes = 256 threads)
  {
    int t4 = c4*64 + lane;
    for (int i = t4; i < HTSZ; i += 256){
      hbuf[group][0][i] = 0u;
      hbuf[group][1][i] = 0u;
    }
  }

  // own B-fragments -> registers (global, L2-hot, coalesced 16B/lane)
  short8 bRh[4], bRl[4], bZh[4], bZl[4], bNih[2], bNil[2], bNhh[2], bNhl[2];
  #pragma unroll
  for (int kt = 0; kt < 4; ++kt){
    int qr = (c4<<2) + kt;
    bRh[kt] = *(const short8*)&Bpk[qr*512 + lane*8];
    bRl[kt] = *(const short8*)&Bpk[24576 + qr*512 + lane*8];
    int qz = 16 + (c4<<2) + kt;
    bZh[kt] = *(const short8*)&Bpk[qz*512 + lane*8];
    bZl[kt] = *(const short8*)&Bpk[24576 + qz*512 + lane*8];
  }
  #pragma unroll
  for (int kt = 0; kt < 2; ++kt){
    int qn = 32 + (c4<<1) + kt;
    bNih[kt] = *(const short8*)&Bpk[qn*512 + lane*8];
    bNil[kt] = *(const short8*)&Bpk[24576 + qn*512 + lane*8];
    int qh = 40 + (c4<<1) + kt;
    bNhh[kt] = *(const short8*)&Bpk[qh*512 + lane*8];
    bNhl[kt] = *(const short8*)&Bpk[24576 + qh*512 + lane*8];
  }

  // biases for this wave's 16 channels
  int jc = c4*16 + n16;
  float bR  = b_ih[jc]      + b_hh[jc];
  float bZ  = b_ih[64+jc]   + b_hh[64+jc];
  float bNi = b_ih[128+jc];
  float bNh = b_hh[128+jc];
  float wfc = W_fc[lane], bfc = b_fc[0];

  floatx4 hreg = (floatx4){0.f,0.f,0.f,0.f};

  int nn = n0 + n16; if (nn > N-1) nn = N-1;
  const float* rbase = rin + (size_t)nn*24;
  float2 rcur = *(const float2*)rbase;

  __syncthreads();

  #pragma unroll 1
  for (int t = 0; t < T_STEPS; ++t){
    float2 rnx = (t < T_STEPS-1) ? *(const float2*)(rbase + 2*(t+1)) : rcur;
    const unsigned* hrd = hbuf[group][t & 1];
    unsigned*       hwr = hbuf[group][(t+1) & 1];

    short8 ahi[4], alo[4];
    // s half (kt 0,1): compute directly in A-frag layout from wgl
    #pragma unroll
    for (int kt = 0; kt < 2; ++kt){
      int j0 = kt*32 + quad*8;
      floatx4 g0a = *(floatx4*)&wgl[j0],       g0b = *(floatx4*)&wgl[j0+4];
      floatx4 g1a = *(floatx4*)&wgl[64 + j0],  g1b = *(floatx4*)&wgl[64 + j0+4];
      floatx4 bga = *(floatx4*)&wgl[128 + j0], bgb = *(floatx4*)&wgl[128 + j0+4];
      float f[8];
      #pragma unroll
      for (int j = 0; j < 4; ++j){
        f[j]   = fmaxf(fmaf(rcur.x, g0a[j], fmaf(rcur.y, g1a[j], bga[j])), 0.f);
        f[4+j] = fmaxf(fmaf(rcur.x, g0b[j], fmaf(rcur.y, g1b[j], bgb[j])), 0.f);
      }
      union { short8 v; unsigned w[4]; } H, L;
      #pragma unroll
      for (int p2 = 0; p2 < 4; ++p2){
        unsigned ua = __float_as_uint(f[2*p2]);
        unsigned ub = __float_as_uint(f[2*p2+1]);
        H.w[p2] = prm(ub, ua, 0x07060302u);
        unsigned ra = __float_as_uint(f[2*p2]   - __uint_as_float(ua & 0xFFFF0000u)) + 0x8000u;
        unsigned rb = __float_as_uint(f[2*p2+1] - __uint_as_float(ub & 0xFFFF0000u)) + 0x8000u;
        L.w[p2] = prm(rb, ra, 0x07060302u);
      }
      ahi[kt] = H.v; alo[kt] = L.v;
    }
    // h half (kt 2,3): packed u32 from shared h-tile, 1 perm/element
    #pragma unroll
    for (int kt = 2; kt < 4; ++kt){
      int base = n16*HSTR2 + (kt-2)*32 + quad*8;
      uint4 wa = *(const uint4*)&hrd[base];
      uint4 wb = *(const uint4*)&hrd[base+4];
      union { short8 v; unsigned w[4]; } H, L;
      H.w[0] = prm(wa.y, wa.x, 0x07060302u); L.w[0] = prm(wa.y, wa.x, 0x05040100u);
      H.w[1] = prm(wa.w, wa.z, 0x07060302u); L.w[1] = prm(wa.w, wa.z, 0x05040100u);
      H.w[2] = prm(wb.y, wb.x, 0x07060302u); L.w[2] = prm(wb.y, wb.x, 0x05040100u);
      H.w[3] = prm(wb.w, wb.z, 0x07060302u); L.w[3] = prm(wb.w, wb.z, 0x05040100u);
      ahi[kt] = H.v; alo[kt] = L.v;
    }

    // 3 independent MFMA chains (R, Z, N) over 4 k-tiles, B all in registers
    floatx4 aR = (floatx4){bR, bR, bR, bR};
    floatx4 aZ = (floatx4){bZ, bZ, bZ, bZ};
    floatx4 aN = (floatx4){bNi, bNi, bNi, bNi};
    floatx4 aH = (floatx4){bNh, bNh, bNh, bNh};
    #pragma unroll
    for (int kt = 0; kt < 4; ++kt){
      aR = __builtin_amdgcn_mfma_f32_16x16x32_bf16(ahi[kt], bRh[kt], aR, 0,0,0);
      aZ = __builtin_amdgcn_mfma_f32_16x16x32_bf16(ahi[kt], bZh[kt], aZ, 0,0,0);
      aR = __builtin_amdgcn_mfma_f32_16x16x32_bf16(alo[kt], bRh[kt], aR, 0,0,0);
      aZ = __builtin_amdgcn_mfma_f32_16x16x32_bf16(alo[kt], bZh[kt], aZ, 0,0,0);
      aR = __builtin_amdgcn_mfma_f32_16x16x32_bf16(ahi[kt], bRl[kt], aR, 0,0,0);
      aZ = __builtin_amdgcn_mfma_f32_16x16x32_bf16(ahi[kt], bZl[kt], aZ, 0,0,0);
      if (kt < 2){
        aN = __builtin_amdgcn_mfma_f32_16x16x32_bf16(ahi[kt], bNih[kt], aN, 0,0,0);
        aN = __builtin_amdgcn_mfma_f32_16x16x32_bf16(alo[kt], bNih[kt], aN, 0,0,0);
        aN = __builtin_amdgcn_mfma_f32_16x16x32_bf16(ahi[kt], bNil[kt], aN, 0,0,0);
      } else {
        aH = __builtin_amdgcn_mfma_f32_16x16x32_bf16(ahi[kt], bNhh[kt-2], aH, 0,0,0);
        aH = __builtin_amdgcn_mfma_f32_16x16x32_bf16(alo[kt], bNhh[kt-2], aH, 0,0,0);
        aH = __builtin_amdgcn_mfma_f32_16x16x32_bf16(ahi[kt], bNhl[kt-2], aH, 0,0,0);
      }
    }

    // epilogue for own 16 channels: C/D row = quad*4+r, col = c4*16+n16
    #pragma unroll
    for (int r = 0; r < 4; ++r){
      float rg = sigmoid2_(aR[r]);
      float zg = sigmoid2_(aZ[r]);
      float ng = tanh2_(aN[r] + rg*aH[r]);
      float hn = (1.f - zg)*ng + zg*hreg[r];
      hreg[r] = hn;
      unsigned hu = __float_as_uint(hn);
      float    rs = hn - __uint_as_float(hu & 0xFFFF0000u);
      unsigned rp = __float_as_uint(rs) + 0x8000u;
      hwr[(quad*4 + r)*HSTR2 + c4*16 + n16] = prm(hu, rp, 0x07060302u);
    }
    rcur = rnx;
    __syncthreads();
  }

  // FC epilogue: final h is in buf[T_STEPS & 1] = buf[0]; wave c4==0 of each
  // group reduces its 16 rows.
  if (c4 == 0){
    const unsigned* hf = hbuf[group][T_STEPS & 1];
    #pragma unroll 1
    for (int m = 0; m < 16; ++m){
      unsigned w = hf[m*HSTR2 + lane];
      float hv = __uint_as_float(w & 0xFFFF0000u) + __uint_as_float(w << 16);
      float v = hv * wfc;
      #pragma unroll
      for (int off = 32; off >= 1; off >>= 1) v += __shfl_xor(v, off, 64);
      int n = n0 + m;
      if (lane == 0 && n < N) out[n] = v + bfc;
    }
  }
}

extern "C" void kernel_launch(void* const* d_in, const int* in_sizes, int n_in,
                              void* d_out, int out_size, void* d_ws, size_t ws_size,
                              hipStream_t stream){
  const float* x     = (const float*)d_in[0];
  const int*   ei    = (const int*)d_in[1];
  const float* W_gcn = (const float*)d_in[2];
  const float* b_gcn = (const float*)d_in[3];
  const float* W_ih  = (const float*)d_in[4];
  const float* W_hh  = (const float*)d_in[5];
  const float* b_ih  = (const float*)d_in[6];
  const float* b_hh  = (const float*)d_in[7];
  const float* W_fc  = (const float*)d_in[8];
  const float* b_fc  = (const float*)d_in[9];
  float* out = (float*)d_out;
  const int N = in_sizes[0] / (T_STEPS*2);
  const int E = in_sizes[1] / 2;
  const int NB1024 = (N + 1023) / 1024;

  char* p = (char*)d_ws;
  auto alloc = [&](size_t bytes)->char*{
    char* r = p; p += (bytes + 255) & ~(size_t)255; return r;
  };
  int*   cnt       = (int*)  alloc((size_t)N*4);
  int*   row_start = (int*)  alloc((size_t)(N+1)*4);
  int*   cursor    = (int*)  alloc((size_t)N*4);
  int*   csr       = (int*)  alloc((size_t)E*4);
  float* dinv      = (float*)alloc((size_t)N*4);
  int*   part      = (int*)  alloc((size_t)N*4);
  int*   bsum      = (int*)  alloc((size_t)NB1024*4);
  int*   bincl     = (int*)  alloc((size_t)NB1024*4);
  float* rin       = (float*)alloc((size_t)N*24*4);
  float* xs        = (float*)alloc((size_t)N*24*4);
  unsigned short* Bpk = (unsigned short*)alloc((size_t)49152*2);

  hipMemsetAsync(cnt, 0, (size_t)N*4, stream);
  count_kernel<<<(E+255)/256, 256, 0, stream>>>(ei, E, cnt);
  dinv_scale_kernel<<<(N*6+255)/256, 256, 0, stream>>>(cnt, x, dinv, (float4*)xs, N);
  scan1_kernel<<<NB1024, 1024, 0, stream>>>(cnt, part, bsum, N);
  scan2_kernel<<<1, 64, 0, stream>>>(bsum, bincl, NB1024);
  scan3_kernel<<<(N+255)/256, 256, 0, stream>>>(part, bincl, cnt, row_start, cursor, N);
  fill_kernel<<<(E+255)/256, 256, 0, stream>>>(ei, E, cursor, csr);
  packB_kernel<<<(48*512+255)/256, 256, 0, stream>>>(W_ih, W_hh, Bpk);
  gather6_kernel<<<(N*6+255)/256, 256, 0, stream>>>((const float4*)xs, row_start, csr,
                                                    dinv, (float4*)rin, N);

  int ntiles = (N + 15) / 16;          // 16-node tiles, 4 waves each
  int blocks = (ntiles + 1) / 2;       // 2 tile-groups (8 waves) per block
  gru4_kernel<<<blocks, 512, 0, stream>>>(rin, W_gcn, b_gcn, Bpk,
                                          b_ih, b_hh, W_fc, b_fc, out, N, ntiles);
}

// Round 12
// 329.088 us; speedup vs baseline: 1.1914x; 1.1914x over previous
//
#include <hip/hip_runtime.h>
#include <hip/hip_fp16.h>
#include <math.h>

#define T_STEPS 12
#define HID 64
#define GWPB 14             // waves per block (224 blocks = 1/CU)
#define GBLOCK (GWPB*64)    // 896 threads
#define HSTR2 68            // h-tile row stride in u32 (64 + 4 pad)
#define B_LDS_BYTES 49152   // 48 slots x 512 fp16 (single-precision-B, fp16)
#define WG_LDS_BYTES 768
#define H_LDS_BYTES (GWPB*16*HSTR2*4)   // 60928
#define LDS_TOTAL (B_LDS_BYTES + WG_LDS_BYTES + H_LDS_BYTES)  // 110848

typedef _Float16 half8 __attribute__((ext_vector_type(8)));
typedef __fp16   fp16x2 __attribute__((ext_vector_type(2)));   // pkrtz result type
typedef __attribute__((ext_vector_type(4))) float floatx4;

__device__ __forceinline__ unsigned prm(unsigned a, unsigned b, unsigned s){
  return __builtin_amdgcn_perm(a, b, s);
}
__device__ __forceinline__ float sigmoid2_(float x){
  return 1.0f/(1.0f + __expf(-x));
}
__device__ __forceinline__ float tanh2_(float x){
  return 1.0f - 2.0f/(1.0f + __expf(2.0f*x));
}
// split f32 pair -> fp16 hi pair + fp16 residual pair (RTZ hi, residual near-exact)
__device__ __forceinline__ void split2(float f0, float f1, unsigned &hi, unsigned &lo){
  fp16x2 h = __builtin_amdgcn_cvt_pkrtz(f0, f1);
  float b0 = (float)h[0], b1 = (float)h[1];
  fp16x2 l = __builtin_amdgcn_cvt_pkrtz(f0 - b0, f1 - b1);
  hi = __builtin_bit_cast(unsigned, h);
  lo = __builtin_bit_cast(unsigned, l);
}

// --- CSR build ----------------------------------------------------------
__global__ void count_kernel(const int* __restrict__ ei, int E, int* __restrict__ cnt){
  int e = blockIdx.x*blockDim.x + threadIdx.x;
  if (e < E) atomicAdd(&cnt[ei[E + e]], 1);
}

__global__ void dinv_scale_kernel(const int* __restrict__ cnt, const float* __restrict__ x,
                                  float* __restrict__ dinv, float4* __restrict__ xs, int N){
  int tid = blockIdx.x*blockDim.x + threadIdx.x;
  if (tid >= N*6) return;
  int n = tid / 6;
  float dn = rsqrtf((float)cnt[n] + 1.0f);
  if ((tid - n*6) == 0) dinv[n] = dn;
  float4 v = ((const float4*)x)[tid];
  xs[tid] = make_float4(dn*v.x, dn*v.y, dn*v.z, dn*v.w);
}

__global__ void scan1_kernel(const int* __restrict__ cnt, int* __restrict__ part,
                             int* __restrict__ bsum, int N){
  __shared__ int sm[1024];
  int tid = threadIdx.x;
  int g = blockIdx.x*1024 + tid;
  int v = (g < N) ? cnt[g] : 0;
  sm[tid] = v; __syncthreads();
  for (int off = 1; off < 1024; off <<= 1){
    int t = (tid >= off) ? sm[tid-off] : 0;
    __syncthreads();
    sm[tid] += t;
    __syncthreads();
  }
  if (g < N) part[g] = sm[tid];
  if (tid == 1023) bsum[blockIdx.x] = sm[1023];
}
__global__ void scan2_kernel(const int* __restrict__ bsum, int* __restrict__ bincl, int nb){
  int lane = threadIdx.x;
  int v = (lane < nb) ? bsum[lane] : 0;
  #pragma unroll
  for (int off = 1; off < 64; off <<= 1){
    int u = __shfl_up(v, off, 64);
    if (lane >= off) v += u;
  }
  if (lane < nb) bincl[lane] = v;
}
__global__ void scan3_kernel(const int* __restrict__ part, const int* __restrict__ bincl,
                             const int* __restrict__ cnt, int* __restrict__ row_start,
                             int* __restrict__ cursor, int N){
  int g = blockIdx.x*blockDim.x + threadIdx.x;
  if (g < N){
    int b = g >> 10;
    int incl = part[g] + (b ? bincl[b-1] : 0);
    int excl = incl - cnt[g];
    row_start[g] = excl;
    cursor[g]    = excl;
    if (g == N-1) row_start[N] = incl;
  }
}
__global__ void fill_kernel(const int* __restrict__ ei, int E,
                            int* __restrict__ cursor, int* __restrict__ csr){
  int e = blockIdx.x*blockDim.x + threadIdx.x;
  if (e < E){
    int dst = ei[E + e];
    int pos = atomicAdd(&cursor[dst], 1);
    csr[pos] = ei[e];  // src
  }
}

__global__ void gather6_kernel(const float4* __restrict__ xs, const int* __restrict__ row_start,
                               const int* __restrict__ csr, const float* __restrict__ dinv,
                               float4* __restrict__ rin, int N){
  int tid = blockIdx.x*blockDim.x + threadIdx.x;
  if (tid >= N*6) return;
  int n = tid / 6;
  int q = tid - n*6;
  int s0 = row_start[n], s1 = row_start[n+1];
  float4 acc = xs[n*6 + q];          // self term
  int e = s0;
  for (; e + 1 < s1; e += 2){
    int sa = csr[e], sb = csr[e+1];
    float4 va = xs[sa*6 + q];
    float4 vb = xs[sb*6 + q];
    acc.x += va.x + vb.x;
    acc.y += va.y + vb.y;
    acc.z += va.z + vb.z;
    acc.w += va.w + vb.w;
  }
  if (e < s1){
    float4 va = xs[csr[e]*6 + q];
    acc.x += va.x; acc.y += va.y; acc.z += va.z; acc.w += va.w;
  }
  float dn = dinv[n];
  rin[tid] = make_float4(dn*acc.x, dn*acc.y, dn*acc.z, dn*acc.w);
}

// Pack weights into fp16 B-fragment layout (round-6 proven slot indexing,
// single fp16 per element — no lo plane).
__global__ void packB_kernel(const float* __restrict__ W_ih, const float* __restrict__ W_hh,
                             unsigned short* __restrict__ Bpk){
  int idx = blockIdx.x*blockDim.x + threadIdx.x;
  if (idx >= 48*512) return;
  int q = idx >> 9;
  int rr = idx & 511;
  int l = rr >> 3, j = rr & 7;
  int g, c4, kt;
  if (q < 32){ g = q >> 4; int rem = q & 15; c4 = rem >> 2; kt = rem & 3; }
  else if (q < 40){ g = 2; c4 = (q-32) >> 1; kt = (q-32) & 1; }
  else            { g = 3; c4 = (q-40) >> 1; kt = ((q-40) & 1) + 2; }
  int k  = kt*32 + (l >> 4)*8 + j;
  int n  = l & 15;
  int jc = c4*16 + n;
  float w;
  if (g == 0)      w = (k < 64) ? W_ih[jc*64 + k]      : W_hh[jc*64 + (k-64)];
  else if (g == 1) w = (k < 64) ? W_ih[(64+jc)*64 + k] : W_hh[(64+jc)*64 + (k-64)];
  else if (g == 2) w = W_ih[(128+jc)*64 + k];
  else             w = W_hh[(128+jc)*64 + (k-64)];
  _Float16 hv = (_Float16)w;   // RNE
  Bpk[q*512 + l*8 + j] = __builtin_bit_cast(unsigned short, hv);
}

// Fused 12-step GRU + FC via fp16 2-term MFMA (Ahi*B + Alo*B; B single fp16).
// Wave-private: wave = 16 nodes, owns all 64 channels, NO barriers in t-loop.
// B (48 KB fp16) block-staged in LDS; h packed (fp16hi|fp16lo per u32) in a
// per-wave 16x68 LDS tile. 14 waves/block, 224 blocks = 1/CU, 3.5 waves/SIMD.
__global__ __attribute__((amdgpu_waves_per_eu(4, 8))) __launch_bounds__(GBLOCK)
void gru16_kernel(const float* __restrict__ rin,
                  const float* __restrict__ W_gcn, const float* __restrict__ b_gcn,
                  const unsigned short* __restrict__ Bpk,
                  const float* __restrict__ b_ih, const float* __restrict__ b_hh,
                  const float* __restrict__ W_fc, const float* __restrict__ b_fc,
                  float* __restrict__ out, int N, int ntiles){
  extern __shared__ char smem[];
  unsigned short* Bl = (unsigned short*)smem;
  float*    wgl = (float*)(smem + B_LDS_BYTES);
  unsigned* hl  = (unsigned*)(smem + B_LDS_BYTES + WG_LDS_BYTES);

  {
    const int4* Bg = (const int4*)Bpk;
    int4* Bd = (int4*)smem;
    for (int i = threadIdx.x; i < 3072; i += GBLOCK) Bd[i] = Bg[i];
    if (threadIdx.x < 64){
      wgl[threadIdx.x]       = W_gcn[threadIdx.x];
      wgl[64 + threadIdx.x]  = W_gcn[64 + threadIdx.x];
      wgl[128 + threadIdx.x] = b_gcn[threadIdx.x];
    }
  }
  __syncthreads();

  int lane = threadIdx.x & 63;
  int wid  = threadIdx.x >> 6;
  int tile = blockIdx.x*GWPB + wid;
  if (tile >= ntiles) return;
  int n0   = tile << 4;
  int quad = lane >> 4;
  int n16  = lane & 15;
  unsigned* hwp = hl + wid*(16*HSTR2);

  for (int i = lane; i < 16*HSTR2; i += 64) hwp[i] = 0u;   // wave-private, no barrier

  float wfc = W_fc[lane], bfc = b_fc[0];
  float bR[4], bZ[4], bNi[4], bNh[4];
  #pragma unroll
  for (int c4 = 0; c4 < 4; ++c4){
    int jc = c4*16 + n16;
    bR[c4]  = b_ih[jc]      + b_hh[jc];
    bZ[c4]  = b_ih[64+jc]   + b_hh[64+jc];
    bNi[c4] = b_ih[128+jc];
    bNh[c4] = b_hh[128+jc];
  }

  floatx4 hreg[4];
  #pragma unroll
  for (int c4 = 0; c4 < 4; ++c4) hreg[c4] = (floatx4){0.f,0.f,0.f,0.f};

  int nn = n0 + n16; if (nn > N-1) nn = N-1;
  const float* rbase = rin + (size_t)nn*24;
  float2 rcur = *(const float2*)rbase;

  #pragma unroll 1
  for (int t = 0; t < T_STEPS; ++t){
    float2 rnx = (t < T_STEPS-1) ? *(const float2*)(rbase + 2*(t+1)) : rcur;

    half8 ahi[4], alo[4];
    // s half (kt 0,1): compute in A-frag layout from wgl, fp16 split
    #pragma unroll
    for (int kt = 0; kt < 2; ++kt){
      int j0 = kt*32 + quad*8;
      floatx4 g0a = *(floatx4*)&wgl[j0],       g0b = *(floatx4*)&wgl[j0+4];
      floatx4 g1a = *(floatx4*)&wgl[64 + j0],  g1b = *(floatx4*)&wgl[64 + j0+4];
      floatx4 bga = *(floatx4*)&wgl[128 + j0], bgb = *(floatx4*)&wgl[128 + j0+4];
      float f[8];
      #pragma unroll
      for (int j = 0; j < 4; ++j){
        f[j]   = fmaxf(fmaf(rcur.x, g0a[j], fmaf(rcur.y, g1a[j], bga[j])), 0.f);
        f[4+j] = fmaxf(fmaf(rcur.x, g0b[j], fmaf(rcur.y, g1b[j], bgb[j])), 0.f);
      }
      union { half8 v; unsigned w[4]; } H, L;
      #pragma unroll
      for (int p2 = 0; p2 < 4; ++p2)
        split2(f[2*p2], f[2*p2+1], H.w[p2], L.w[p2]);
      ahi[kt] = H.v; alo[kt] = L.v;
    }
    // h half (kt 2,3): packed u32 (hi low16, lo high16), 1 perm/element
    #pragma unroll
    for (int kt = 2; kt < 4; ++kt){
      int base = n16*HSTR2 + (kt-2)*32 + quad*8;
      uint4 wa = *(const uint4*)&hwp[base];
      uint4 wb = *(const uint4*)&hwp[base+4];
      union { half8 v; unsigned w[4]; } H, L;
      H.w[0] = prm(wa.y, wa.x, 0x05040100u); L.w[0] = prm(wa.y, wa.x, 0x07060302u);
      H.w[1] = prm(wa.w, wa.z, 0x05040100u); L.w[1] = prm(wa.w, wa.z, 0x07060302u);
      H.w[2] = prm(wb.y, wb.x, 0x05040100u); L.w[2] = prm(wb.y, wb.x, 0x07060302u);
      H.w[3] = prm(wb.w, wb.z, 0x05040100u); L.w[3] = prm(wb.w, wb.z, 0x07060302u);
      ahi[kt] = H.v; alo[kt] = L.v;
    }

    #pragma unroll
    for (int c4 = 0; c4 < 4; ++c4){
      floatx4 aR = (floatx4){bR[c4], bR[c4], bR[c4], bR[c4]};
      floatx4 aZ = (floatx4){bZ[c4], bZ[c4], bZ[c4], bZ[c4]};
      floatx4 aN = (floatx4){bNi[c4],bNi[c4],bNi[c4],bNi[c4]};
      floatx4 aH = (floatx4){bNh[c4],bNh[c4],bNh[c4],bNh[c4]};
      #pragma unroll
      for (int kt = 0; kt < 4; ++kt){
        int qr = (c4<<2) + kt;
        half8 wR = *(const half8*)&Bl[qr*512 + lane*8];
        aR = __builtin_amdgcn_mfma_f32_16x16x32_f16(ahi[kt], wR, aR, 0,0,0);
        aR = __builtin_amdgcn_mfma_f32_16x16x32_f16(alo[kt], wR, aR, 0,0,0);
        int qz = 16 + (c4<<2) + kt;
        half8 wZ = *(const half8*)&Bl[qz*512 + lane*8];
        aZ = __builtin_amdgcn_mfma_f32_16x16x32_f16(ahi[kt], wZ, aZ, 0,0,0);
        aZ = __builtin_amdgcn_mfma_f32_16x16x32_f16(alo[kt], wZ, aZ, 0,0,0);
        if (kt < 2){
          int qn = 32 + (c4<<1) + kt;
          half8 wN = *(const half8*)&Bl[qn*512 + lane*8];
          aN = __builtin_amdgcn_mfma_f32_16x16x32_f16(ahi[kt], wN, aN, 0,0,0);
          aN = __builtin_amdgcn_mfma_f32_16x16x32_f16(alo[kt], wN, aN, 0,0,0);
        } else {
          int qh = 40 + (c4<<1) + (kt-2);
          half8 wH = *(const half8*)&Bl[qh*512 + lane*8];
          aH = __builtin_amdgcn_mfma_f32_16x16x32_f16(ahi[kt], wH, aH, 0,0,0);
          aH = __builtin_amdgcn_mfma_f32_16x16x32_f16(alo[kt], wH, aH, 0,0,0);
        }
      }
      // epilogue: C/D row = quad*4+r, col = c4*16+n16
      #pragma unroll
      for (int r = 0; r < 4; ++r){
        float rg = sigmoid2_(aR[r]);
        float zg = sigmoid2_(aZ[r]);
        float ng = tanh2_(aN[r] + rg*aH[r]);
        float hn = (1.f - zg)*ng + zg*hreg[c4][r];
        hreg[c4][r] = hn;
        fp16x2 t0 = __builtin_amdgcn_cvt_pkrtz(hn, hn);
        float back = (float)t0[0];
        fp16x2 pw = __builtin_amdgcn_cvt_pkrtz(hn, hn - back);
        hwp[(quad*4 + r)*HSTR2 + c4*16 + n16] = __builtin_bit_cast(unsigned, pw);
      }
    }
    rcur = rnx;
  }

  // FC epilogue: reconstruct h = hi + lo
  #pragma unroll 1
  for (int m = 0; m < 16; ++m){
    fp16x2 hw2 = __builtin_bit_cast(fp16x2, hwp[m*HSTR2 + lane]);
    float hv = (float)hw2[0] + (float)hw2[1];
    float v = hv * wfc;
    #pragma unroll
    for (int off = 32; off >= 1; off >>= 1) v += __shfl_xor(v, off, 64);
    int n = n0 + m;
    if (lane == 0 && n < N) out[n] = v + bfc;
  }
}

extern "C" void kernel_launch(void* const* d_in, const int* in_sizes, int n_in,
                              void* d_out, int out_size, void* d_ws, size_t ws_size,
                              hipStream_t stream){
  const float* x     = (const float*)d_in[0];
  const int*   ei    = (const int*)d_in[1];
  const float* W_gcn = (const float*)d_in[2];
  const float* b_gcn = (const float*)d_in[3];
  const float* W_ih  = (const float*)d_in[4];
  const float* W_hh  = (const float*)d_in[5];
  const float* b_ih  = (const float*)d_in[6];
  const float* b_hh  = (const float*)d_in[7];
  const float* W_fc  = (const float*)d_in[8];
  const float* b_fc  = (const float*)d_in[9];
  float* out = (float*)d_out;
  const int N = in_sizes[0] / (T_STEPS*2);
  const int E = in_sizes[1] / 2;
  const int NB1024 = (N + 1023) / 1024;

  char* p = (char*)d_ws;
  auto alloc = [&](size_t bytes)->char*{
    char* r = p; p += (bytes + 255) & ~(size_t)255; return r;
  };
  int*   cnt       = (int*)  alloc((size_t)N*4);
  int*   row_start = (int*)  alloc((size_t)(N+1)*4);
  int*   cursor    = (int*)  alloc((size_t)N*4);
  int*   csr       = (int*)  alloc((size_t)E*4);
  float* dinv      = (float*)alloc((size_t)N*4);
  int*   part      = (int*)  alloc((size_t)N*4);
  int*   bsum      = (int*)  alloc((size_t)NB1024*4);
  int*   bincl     = (int*)  alloc((size_t)NB1024*4);
  float* rin       = (float*)alloc((size_t)N*24*4);
  float* xs        = (float*)alloc((size_t)N*24*4);
  unsigned short* Bpk = (unsigned short*)alloc((size_t)24576*2);

  hipMemsetAsync(cnt, 0, (size_t)N*4, stream);
  count_kernel<<<(E+255)/256, 256, 0, stream>>>(ei, E, cnt);
  dinv_scale_kernel<<<(N*6+255)/256, 256, 0, stream>>>(cnt, x, dinv, (float4*)xs, N);
  scan1_kernel<<<NB1024, 1024, 0, stream>>>(cnt, part, bsum, N);
  scan2_kernel<<<1, 64, 0, stream>>>(bsum, bincl, NB1024);
  scan3_kernel<<<(N+255)/256, 256, 0, stream>>>(part, bincl, cnt, row_start, cursor, N);
  fill_kernel<<<(E+255)/256, 256, 0, stream>>>(ei, E, cursor, csr);
  packB_kernel<<<(48*512+255)/256, 256, 0, stream>>>(W_ih, W_hh, Bpk);
  gather6_kernel<<<(N*6+255)/256, 256, 0, stream>>>((const float4*)xs, row_start, csr,
                                                    dinv, (float4*)rin, N);

  (void)hipFuncSetAttribute((const void*)gru16_kernel,
                            hipFuncAttributeMaxDynamicSharedMemorySize, LDS_TOTAL);
  int ntiles = (N + 15) / 16;                      // 3125
  int blocks = (ntiles + GWPB - 1) / GWPB;         // 224
  gru16_kernel<<<blocks, GBLOCK, LDS_TOTAL, stream>>>(rin, W_gcn, b_gcn, Bpk,
                                                      b_ih, b_hh, W_fc, b_fc,
                                                      out, N, ntiles);
}

// Round 13
// 317.991 us; speedup vs baseline: 1.2330x; 1.0349x over previous
//
#include <hip/hip_runtime.h>
#include <hip/hip_fp16.h>
#include <math.h>

#define T_STEPS 12
#define HID 64
#define GWPB 14             // waves per block (224 blocks = 1/CU)
#define GBLOCK (GWPB*64)    // 896 threads
#define HSTR2 68            // h-tile row stride in u32 (64 + 4 pad)
#define B_LDS_BYTES 49152   // 48 slots x 512 fp16 (single-precision-B, fp16)
#define WG_LDS_BYTES 768
#define H_LDS_BYTES (GWPB*16*HSTR2*4)   // 60928
#define LDS_TOTAL (B_LDS_BYTES + WG_LDS_BYTES + H_LDS_BYTES)  // 110848

typedef _Float16 half8 __attribute__((ext_vector_type(8)));
typedef __fp16   fp16x2 __attribute__((ext_vector_type(2)));   // pkrtz result type
typedef __attribute__((ext_vector_type(4))) float floatx4;

__device__ __forceinline__ unsigned prm(unsigned a, unsigned b, unsigned s){
  return __builtin_amdgcn_perm(a, b, s);
}
__device__ __forceinline__ float sigmoid2_(float x){
  return 1.0f/(1.0f + __expf(-x));
}
__device__ __forceinline__ float tanh2_(float x){
  return 1.0f - 2.0f/(1.0f + __expf(2.0f*x));
}
// split f32 pair -> fp16 hi pair + fp16 residual pair (RTZ hi, residual near-exact)
__device__ __forceinline__ void split2(float f0, float f1, unsigned &hi, unsigned &lo){
  fp16x2 h = __builtin_amdgcn_cvt_pkrtz(f0, f1);
  float b0 = (float)h[0], b1 = (float)h[1];
  fp16x2 l = __builtin_amdgcn_cvt_pkrtz(f0 - b0, f1 - b1);
  hi = __builtin_bit_cast(unsigned, h);
  lo = __builtin_bit_cast(unsigned, l);
}

// --- CSR build ----------------------------------------------------------
__global__ void count_kernel(const int* __restrict__ ei, int E, int* __restrict__ cnt){
  int e = blockIdx.x*blockDim.x + threadIdx.x;
  if (e < E) atomicAdd(&cnt[ei[E + e]], 1);
}

__global__ void dinv_scale_kernel(const int* __restrict__ cnt, const float* __restrict__ x,
                                  float* __restrict__ dinv, float4* __restrict__ xs, int N){
  int tid = blockIdx.x*blockDim.x + threadIdx.x;
  if (tid >= N*6) return;
  int n = tid / 6;
  float dn = rsqrtf((float)cnt[n] + 1.0f);
  if ((tid - n*6) == 0) dinv[n] = dn;
  float4 v = ((const float4*)x)[tid];
  xs[tid] = make_float4(dn*v.x, dn*v.y, dn*v.z, dn*v.w);
}

// per-1024-block inclusive scan: wave shfl-scan + cross-wave fixup (2 barriers)
__global__ void scan1_kernel(const int* __restrict__ cnt, int* __restrict__ part,
                             int* __restrict__ bsum, int N){
  __shared__ int wsum[16];
  int tid = threadIdx.x;
  int g = blockIdx.x*1024 + tid;
  int v = (g < N) ? cnt[g] : 0;
  int lane = tid & 63, wv = tid >> 6;
  int s = v;
  #pragma unroll
  for (int off = 1; off < 64; off <<= 1){
    int u = __shfl_up(s, off, 64);
    if (lane >= off) s += u;
  }
  if (lane == 63) wsum[wv] = s;
  __syncthreads();
  if (wv == 0){
    int w = (lane < 16) ? wsum[lane] : 0;
    #pragma unroll
    for (int off = 1; off < 16; off <<= 1){
      int u = __shfl_up(w, off, 64);
      if (lane >= off) w += u;
    }
    if (lane < 16) wsum[lane] = w;
  }
  __syncthreads();
  int incl = (wv ? wsum[wv-1] : 0) + s;
  if (g < N) part[g] = incl;
  if (tid == 1023) bsum[blockIdx.x] = incl;
}

__global__ void scan2_kernel(const int* __restrict__ bsum, int* __restrict__ bincl, int nb){
  int lane = threadIdx.x;
  int v = (lane < nb) ? bsum[lane] : 0;
  #pragma unroll
  for (int off = 1; off < 64; off <<= 1){
    int u = __shfl_up(v, off, 64);
    if (lane >= off) v += u;
  }
  if (lane < nb) bincl[lane] = v;
}
__global__ void scan3_kernel(const int* __restrict__ part, const int* __restrict__ bincl,
                             const int* __restrict__ cnt, int* __restrict__ row_start,
                             int* __restrict__ cursor, int N){
  int g = blockIdx.x*blockDim.x + threadIdx.x;
  if (g < N){
    int b = g >> 10;
    int incl = part[g] + (b ? bincl[b-1] : 0);
    int excl = incl - cnt[g];
    row_start[g] = excl;
    cursor[g]    = excl;
    if (g == N-1) row_start[N] = incl;
  }
}
__global__ void fill_kernel(const int* __restrict__ ei, int E,
                            int* __restrict__ cursor, int* __restrict__ csr){
  int e = blockIdx.x*blockDim.x + threadIdx.x;
  if (e < E){
    int dst = ei[E + e];
    int pos = atomicAdd(&cursor[dst], 1);
    csr[pos] = ei[e];  // src
  }
}

__global__ void gather6_kernel(const float4* __restrict__ xs, const int* __restrict__ row_start,
                               const int* __restrict__ csr, const float* __restrict__ dinv,
                               float4* __restrict__ rin, int N){
  int tid = blockIdx.x*blockDim.x + threadIdx.x;
  if (tid >= N*6) return;
  int n = tid / 6;
  int q = tid - n*6;
  int s0 = row_start[n], s1 = row_start[n+1];
  float4 acc = xs[n*6 + q];          // self term
  int e = s0;
  for (; e + 1 < s1; e += 2){
    int sa = csr[e], sb = csr[e+1];
    float4 va = xs[sa*6 + q];
    float4 vb = xs[sb*6 + q];
    acc.x += va.x + vb.x;
    acc.y += va.y + vb.y;
    acc.z += va.z + vb.z;
    acc.w += va.w + vb.w;
  }
  if (e < s1){
    float4 va = xs[csr[e]*6 + q];
    acc.x += va.x; acc.y += va.y; acc.z += va.z; acc.w += va.w;
  }
  float dn = dinv[n];
  rin[tid] = make_float4(dn*acc.x, dn*acc.y, dn*acc.z, dn*acc.w);
}

// Pack weights into fp16 B-fragment layout (round-6 proven slot indexing,
// single fp16 per element — no lo plane).
__global__ void packB_kernel(const float* __restrict__ W_ih, const float* __restrict__ W_hh,
                             unsigned short* __restrict__ Bpk){
  int idx = blockIdx.x*blockDim.x + threadIdx.x;
  if (idx >= 48*512) return;
  int q = idx >> 9;
  int rr = idx & 511;
  int l = rr >> 3, j = rr & 7;
  int g, c4, kt;
  if (q < 32){ g = q >> 4; int rem = q & 15; c4 = rem >> 2; kt = rem & 3; }
  else if (q < 40){ g = 2; c4 = (q-32) >> 1; kt = (q-32) & 1; }
  else            { g = 3; c4 = (q-40) >> 1; kt = ((q-40) & 1) + 2; }
  int k  = kt*32 + (l >> 4)*8 + j;
  int n  = l & 15;
  int jc = c4*16 + n;
  float w;
  if (g == 0)      w = (k < 64) ? W_ih[jc*64 + k]      : W_hh[jc*64 + (k-64)];
  else if (g == 1) w = (k < 64) ? W_ih[(64+jc)*64 + k] : W_hh[(64+jc)*64 + (k-64)];
  else if (g == 2) w = W_ih[(128+jc)*64 + k];
  else             w = W_hh[(128+jc)*64 + (k-64)];
  _Float16 hv = (_Float16)w;   // RNE
  Bpk[q*512 + l*8 + j] = __builtin_bit_cast(unsigned short, hv);
}

// Fused 12-step GRU + FC via fp16 2-term MFMA (Ahi*B + Alo*B; B single fp16).
// Wave-private: wave = 16 nodes, owns all 64 channels, NO barriers in t-loop.
// B (48 KB fp16) block-staged in LDS; h packed (fp16hi|fp16lo per u32) in a
// per-wave 16x68 LDS tile. 14 waves/block, 224 blocks = 1/CU.
// waves_per_eu(1,4): MAX arg sets the VGPR budget target — (·,8) in r12 gave
// a 64-VGPR alloc + 56 MB of scratch spill traffic; max=4 -> 128-VGPR budget.
__global__ __attribute__((amdgpu_waves_per_eu(1, 4))) __launch_bounds__(GBLOCK)
void gru16_kernel(const float* __restrict__ rin,
                  const float* __restrict__ W_gcn, const float* __restrict__ b_gcn,
                  const unsigned short* __restrict__ Bpk,
                  const float* __restrict__ b_ih, const float* __restrict__ b_hh,
                  const float* __restrict__ W_fc, const float* __restrict__ b_fc,
                  float* __restrict__ out, int N, int ntiles){
  extern __shared__ char smem[];
  unsigned short* Bl = (unsigned short*)smem;
  float*    wgl = (float*)(smem + B_LDS_BYTES);
  unsigned* hl  = (unsigned*)(smem + B_LDS_BYTES + WG_LDS_BYTES);

  {
    const int4* Bg = (const int4*)Bpk;
    int4* Bd = (int4*)smem;
    for (int i = threadIdx.x; i < 3072; i += GBLOCK) Bd[i] = Bg[i];
    if (threadIdx.x < 64){
      wgl[threadIdx.x]       = W_gcn[threadIdx.x];
      wgl[64 + threadIdx.x]  = W_gcn[64 + threadIdx.x];
      wgl[128 + threadIdx.x] = b_gcn[threadIdx.x];
    }
  }
  __syncthreads();

  int lane = threadIdx.x & 63;
  int wid  = threadIdx.x >> 6;
  int tile = blockIdx.x*GWPB + wid;
  if (tile >= ntiles) return;
  int n0   = tile << 4;
  int quad = lane >> 4;
  int n16  = lane & 15;
  unsigned* hwp = hl + wid*(16*HSTR2);

  for (int i = lane; i < 16*HSTR2; i += 64) hwp[i] = 0u;   // wave-private, no barrier

  float wfc = W_fc[lane], bfc = b_fc[0];
  float bR[4], bZ[4], bNi[4], bNh[4];
  #pragma unroll
  for (int c4 = 0; c4 < 4; ++c4){
    int jc = c4*16 + n16;
    bR[c4]  = b_ih[jc]      + b_hh[jc];
    bZ[c4]  = b_ih[64+jc]   + b_hh[64+jc];
    bNi[c4] = b_ih[128+jc];
    bNh[c4] = b_hh[128+jc];
  }

  floatx4 hreg[4];
  #pragma unroll
  for (int c4 = 0; c4 < 4; ++c4) hreg[c4] = (floatx4){0.f,0.f,0.f,0.f};

  int nn = n0 + n16; if (nn > N-1) nn = N-1;
  const float* rbase = rin + (size_t)nn*24;
  float2 rcur = *(const float2*)rbase;

  #pragma unroll 1
  for (int t = 0; t < T_STEPS; ++t){
    float2 rnx = (t < T_STEPS-1) ? *(const float2*)(rbase + 2*(t+1)) : rcur;

    half8 ahi[4], alo[4];
    // s half (kt 0,1): compute in A-frag layout from wgl, fp16 split
    #pragma unroll
    for (int kt = 0; kt < 2; ++kt){
      int j0 = kt*32 + quad*8;
      floatx4 g0a = *(floatx4*)&wgl[j0],       g0b = *(floatx4*)&wgl[j0+4];
      floatx4 g1a = *(floatx4*)&wgl[64 + j0],  g1b = *(floatx4*)&wgl[64 + j0+4];
      floatx4 bga = *(floatx4*)&wgl[128 + j0], bgb = *(floatx4*)&wgl[128 + j0+4];
      float f[8];
      #pragma unroll
      for (int j = 0; j < 4; ++j){
        f[j]   = fmaxf(fmaf(rcur.x, g0a[j], fmaf(rcur.y, g1a[j], bga[j])), 0.f);
        f[4+j] = fmaxf(fmaf(rcur.x, g0b[j], fmaf(rcur.y, g1b[j], bgb[j])), 0.f);
      }
      union { half8 v; unsigned w[4]; } H, L;
      #pragma unroll
      for (int p2 = 0; p2 < 4; ++p2)
        split2(f[2*p2], f[2*p2+1], H.w[p2], L.w[p2]);
      ahi[kt] = H.v; alo[kt] = L.v;
    }
    // h half (kt 2,3): packed u32 (hi low16, lo high16), 1 perm/element
    #pragma unroll
    for (int kt = 2; kt < 4; ++kt){
      int base = n16*HSTR2 + (kt-2)*32 + quad*8;
      uint4 wa = *(const uint4*)&hwp[base];
      uint4 wb = *(const uint4*)&hwp[base+4];
      union { half8 v; unsigned w[4]; } H, L;
      H.w[0] = prm(wa.y, wa.x, 0x05040100u); L.w[0] = prm(wa.y, wa.x, 0x07060302u);
      H.w[1] = prm(wa.w, wa.z, 0x05040100u); L.w[1] = prm(wa.w, wa.z, 0x07060302u);
      H.w[2] = prm(wb.y, wb.x, 0x05040100u); L.w[2] = prm(wb.y, wb.x, 0x07060302u);
      H.w[3] = prm(wb.w, wb.z, 0x05040100u); L.w[3] = prm(wb.w, wb.z, 0x07060302u);
      ahi[kt] = H.v; alo[kt] = L.v;
    }

    #pragma unroll
    for (int c4 = 0; c4 < 4; ++c4){
      floatx4 aR = (floatx4){bR[c4], bR[c4], bR[c4], bR[c4]};
      floatx4 aZ = (floatx4){bZ[c4], bZ[c4], bZ[c4], bZ[c4]};
      floatx4 aN = (floatx4){bNi[c4],bNi[c4],bNi[c4],bNi[c4]};
      floatx4 aH = (floatx4){bNh[c4],bNh[c4],bNh[c4],bNh[c4]};
      #pragma unroll
      for (int kt = 0; kt < 4; ++kt){
        int qr = (c4<<2) + kt;
        half8 wR = *(const half8*)&Bl[qr*512 + lane*8];
        aR = __builtin_amdgcn_mfma_f32_16x16x32_f16(ahi[kt], wR, aR, 0,0,0);
        aR = __builtin_amdgcn_mfma_f32_16x16x32_f16(alo[kt], wR, aR, 0,0,0);
        int qz = 16 + (c4<<2) + kt;
        half8 wZ = *(const half8*)&Bl[qz*512 + lane*8];
        aZ = __builtin_amdgcn_mfma_f32_16x16x32_f16(ahi[kt], wZ, aZ, 0,0,0);
        aZ = __builtin_amdgcn_mfma_f32_16x16x32_f16(alo[kt], wZ, aZ, 0,0,0);
        if (kt < 2){
          int qn = 32 + (c4<<1) + kt;
          half8 wN = *(const half8*)&Bl[qn*512 + lane*8];
          aN = __builtin_amdgcn_mfma_f32_16x16x32_f16(ahi[kt], wN, aN, 0,0,0);
          aN = __builtin_amdgcn_mfma_f32_16x16x32_f16(alo[kt], wN, aN, 0,0,0);
        } else {
          int qh = 40 + (c4<<1) + (kt-2);
          half8 wH = *(const half8*)&Bl[qh*512 + lane*8];
          aH = __builtin_amdgcn_mfma_f32_16x16x32_f16(ahi[kt], wH, aH, 0,0,0);
          aH = __builtin_amdgcn_mfma_f32_16x16x32_f16(alo[kt], wH, aH, 0,0,0);
        }
      }
      // epilogue: C/D row = quad*4+r, col = c4*16+n16
      #pragma unroll
      for (int r = 0; r < 4; ++r){
        float rg = sigmoid2_(aR[r]);
        float zg = sigmoid2_(aZ[r]);
        float ng = tanh2_(aN[r] + rg*aH[r]);
        float hn = (1.f - zg)*ng + zg*hreg[c4][r];
        hreg[c4][r] = hn;
        fp16x2 t0 = __builtin_amdgcn_cvt_pkrtz(hn, hn);
        float back = (float)t0[0];
        fp16x2 pw = __builtin_amdgcn_cvt_pkrtz(hn, hn - back);
        hwp[(quad*4 + r)*HSTR2 + c4*16 + n16] = __builtin_bit_cast(unsigned, pw);
      }
    }
    rcur = rnx;
  }

  // FC epilogue: reconstruct h = hi + lo
  #pragma unroll 1
  for (int m = 0; m < 16; ++m){
    fp16x2 hw2 = __builtin_bit_cast(fp16x2, hwp[m*HSTR2 + lane]);
    float hv = (float)hw2[0] + (float)hw2[1];
    float v = hv * wfc;
    #pragma unroll
    for (int off = 32; off >= 1; off >>= 1) v += __shfl_xor(v, off, 64);
    int n = n0 + m;
    if (lane == 0 && n < N) out[n] = v + bfc;
  }
}

extern "C" void kernel_launch(void* const* d_in, const int* in_sizes, int n_in,
                              void* d_out, int out_size, void* d_ws, size_t ws_size,
                              hipStream_t stream){
  const float* x     = (const float*)d_in[0];
  const int*   ei    = (const int*)d_in[1];
  const float* W_gcn = (const float*)d_in[2];
  const float* b_gcn = (const float*)d_in[3];
  const float* W_ih  = (const float*)d_in[4];
  const float* W_hh  = (const float*)d_in[5];
  const float* b_ih  = (const float*)d_in[6];
  const float* b_hh  = (const float*)d_in[7];
  const float* W_fc  = (const float*)d_in[8];
  const float* b_fc  = (const float*)d_in[9];
  float* out = (float*)d_out;
  const int N = in_sizes[0] / (T_STEPS*2);
  const int E = in_sizes[1] / 2;
  const int NB1024 = (N + 1023) / 1024;

  char* p = (char*)d_ws;
  auto alloc = [&](size_t bytes)->char*{
    char* r = p; p += (bytes + 255) & ~(size_t)255; return r;
  };
  int*   cnt       = (int*)  alloc((size_t)N*4);
  int*   row_start = (int*)  alloc((size_t)(N+1)*4);
  int*   cursor    = (int*)  alloc((size_t)N*4);
  int*   csr       = (int*)  alloc((size_t)E*4);
  float* dinv      = (float*)alloc((size_t)N*4);
  int*   part      = (int*)  alloc((size_t)N*4);
  int*   bsum      = (int*)  alloc((size_t)NB1024*4);
  int*   bincl     = (int*)  alloc((size_t)NB1024*4);
  float* rin       = (float*)alloc((size_t)N*24*4);
  float* xs        = (float*)alloc((size_t)N*24*4);
  unsigned short* Bpk = (unsigned short*)alloc((size_t)24576*2);

  hipMemsetAsync(cnt, 0, (size_t)N*4, stream);
  count_kernel<<<(E+255)/256, 256, 0, stream>>>(ei, E, cnt);
  dinv_scale_kernel<<<(N*6+255)/256, 256, 0, stream>>>(cnt, x, dinv, (float4*)xs, N);
  scan1_kernel<<<NB1024, 1024, 0, stream>>>(cnt, part, bsum, N);
  scan2_kernel<<<1, 64, 0, stream>>>(bsum, bincl, NB1024);
  scan3_kernel<<<(N+255)/256, 256, 0, stream>>>(part, bincl, cnt, row_start, cursor, N);
  fill_kernel<<<(E+255)/256, 256, 0, stream>>>(ei, E, cursor, csr);
  packB_kernel<<<(48*512+255)/256, 256, 0, stream>>>(W_ih, W_hh, Bpk);
  gather6_kernel<<<(N*6+255)/256, 256, 0, stream>>>((const float4*)xs, row_start, csr,
                                                    dinv, (float4*)rin, N);

  (void)hipFuncSetAttribute((const void*)gru16_kernel,
                            hipFuncAttributeMaxDynamicSharedMemorySize, LDS_TOTAL);
  int ntiles = (N + 15) / 16;                      // 3125
  int blocks = (ntiles + GWPB - 1) / GWPB;         // 224
  gru16_kernel<<<blocks, GBLOCK, LDS_TOTAL, stream>>>(rin, W_gcn, b_gcn, Bpk,
                                                      b_ih, b_hh, W_fc, b_fc,
                                                      out, N, ntiles);
}